// Round 4
// baseline (155.513 us; speedup 1.0000x reference)
//
#include <hip/hip_runtime.h>
#include <stdint.h>

// Viterbi decoder forward: B=32, T=256, L=48, START=46, END=47.
// 32 WGs Viterbi (max/argmax + traceback) + 32 WGs logsumexp.
// Per WG: 4 waves, i-split 12/wave, lane = target label j.
// R4: emissions staged global->LDS via global_load_lds DMA (8-row ring,
// 4-row groups, counted vmcnt, 3-step landing window); per-step emission
// values prefetched LDS->reg one row ahead; split value/index partials;
// LSE state kept in log2 domain. Raw lgkm-only barriers throughout.

#define TT 256
#define LL 48
#define ROWF 2304      // floats per row (48*48)
#define LSTART 46
#define LEND 47
#define BB 32
#define NL 64
#define LOG2E 1.44269504088896f
#define LN2 0.693147180559945f

#define GLL(GP, LP) __builtin_amdgcn_global_load_lds( \
    (const __attribute__((address_space(1))) void*)(GP), \
    (__attribute__((address_space(3))) void*)(LP), 16, 0, 0)

#define FENCE() asm volatile("" ::: "memory")
#define WAIT_PLAIN() asm volatile("s_waitcnt lgkmcnt(0)" ::: "memory")
#define WAIT_VM0()   asm volatile("s_waitcnt vmcnt(0) lgkmcnt(0)" ::: "memory")

// strict > with ordered pairing == jnp.argmax first-occurrence semantics
#define AMAX(vx, ix, vy, iy) do { if ((vy) > (vx)) { (vx)=(vy); (ix)=(iy);} } while(0)
#define RL(var, lane) __int_as_float(__builtin_amdgcn_readlane(__float_as_int(var), (lane)))

// DMA one 4-row group (36864 B): 9 insts/wave, 1024 B each, linear LDS.
#define ISSUE_GROUP(GR0, HB) do { \
    const float* gs_ = em_lane + (size_t)(GR0)*ROWF; \
    float* ls_ = ring + (HB); \
    _Pragma("unroll") \
    for (int ii = 0; ii < 9; ++ii) \
      GLL(gs_ + (w*9+ii)*256, ls_ + (w*9+ii)*256); \
  } while (0)

// One Viterbi step. ETRC = this row's (emission+trans) in regs;
// prefetches row T_+1 into ETRN. One raw barrier.
#define STEP_V(ETRC, ETRN, T_, WAITM) do { \
    const int PAR_ = (T_) & 1; \
    float en_[12]; \
    { const float* lp_ = ring + (size_t)(((T_)+1)&7)*ROWF + jl; \
      _Pragma("unroll") \
      for (int k = 0; k < 12; ++k) en_[k] = lp_[(12*w+k)*LL]; } \
    float cv[12]; int ci[12]; \
    _Pragma("unroll") \
    for (int k = 0; k < 12; ++k) { \
      cv[k] = (ETRC)[k] + RL(vbest, lanebase+k); ci[k] = lanebase+k; } \
    AMAX(cv[0],ci[0],cv[1],ci[1]);  AMAX(cv[2],ci[2],cv[3],ci[3]); \
    AMAX(cv[4],ci[4],cv[5],ci[5]);  AMAX(cv[6],ci[6],cv[7],ci[7]); \
    AMAX(cv[8],ci[8],cv[9],ci[9]);  AMAX(cv[10],ci[10],cv[11],ci[11]); \
    AMAX(cv[0],ci[0],cv[2],ci[2]);  AMAX(cv[4],ci[4],cv[6],ci[6]); \
    AMAX(cv[8],ci[8],cv[10],ci[10]); \
    AMAX(cv[0],ci[0],cv[4],ci[4]); \
    AMAX(cv[0],ci[0],cv[8],ci[8]); \
    partVal[PAR_][w][j] = cv[0]; \
    partIdx[PAR_][w][j] = ci[0]; \
    _Pragma("unroll") \
    for (int k = 0; k < 12; ++k) (ETRN)[k] = en_[k] + trg[k]; \
    WAITM(); \
    __builtin_amdgcn_s_barrier(); \
    FENCE(); \
    float v0_ = partVal[PAR_][0][j], v1_ = partVal[PAR_][1][j]; \
    float v2_ = partVal[PAR_][2][j], v3_ = partVal[PAR_][3][j]; \
    const bool upd_ = act && ((T_) < len); \
    float bv_ = fmaxf(fmaxf(v0_, v1_), fmaxf(v2_, v3_)); \
    vbest = upd_ ? bv_ : vbest; \
    if (w == 0 && upd_) { \
      float bx_ = v0_; int ba_ = partIdx[PAR_][0][j]; \
      AMAX(bx_, ba_, v1_, partIdx[PAR_][1][j]); \
      AMAX(bx_, ba_, v2_, partIdx[PAR_][2][j]); \
      AMAX(bx_, ba_, v3_, partIdx[PAR_][3][j]); \
      bp[(T_)*LL + j] = (unsigned char)ba_; \
    } \
  } while (0)

// One LSE step, state in log2 domain: vupto2 = upto*log2e.
// shift = vupto2[0]; spread across labels is bounded -> no overflow.
#define STEP_L(ETRC, ETRN, T_, WAITM) do { \
    const int PAR_ = (T_) & 1; \
    float en_[12]; \
    { const float* lp_ = ring + (size_t)(((T_)+1)&7)*ROWF + jl; \
      _Pragma("unroll") \
      for (int k = 0; k < 12; ++k) en_[k] = lp_[(12*w+k)*LL]; } \
    float ex[12]; \
    _Pragma("unroll") \
    for (int k = 0; k < 12; ++k) { \
      float d_ = (ETRC)[k] - msh2; \
      ex[k] = exp2f(d_ + RL(vupto2, lanebase+k)); \
    } \
    float s01=ex[0]+ex[1], s23=ex[2]+ex[3], s45=ex[4]+ex[5]; \
    float s67=ex[6]+ex[7], s89=ex[8]+ex[9], sab=ex[10]+ex[11]; \
    partVal[PAR_][w][j] = ((s01+s23)+(s45+s67))+(s89+sab); \
    _Pragma("unroll") \
    for (int k = 0; k < 12; ++k) (ETRN)[k] = (en_[k] + trg[k]) * LOG2E; \
    WAITM(); \
    __builtin_amdgcn_s_barrier(); \
    FENCE(); \
    float sum_ = (partVal[PAR_][0][j] + partVal[PAR_][1][j]) \
               + (partVal[PAR_][2][j] + partVal[PAR_][3][j]); \
    float nu_ = msh2 + __log2f(sum_); \
    const bool upd_ = act && ((T_) < len); \
    vupto2 = upd_ ? nu_ : vupto2; \
    msh2 = RL(vupto2, 0); \
  } while (0)

__launch_bounds__(256, 1)
__global__ void viterbi_fwd(const float* __restrict__ em,
                            const float* __restrict__ tr,
                            const int* __restrict__ len_raw,
                            float* __restrict__ out,
                            float* __restrict__ ws)
{
  const int role = blockIdx.x >> 5;   // 0 = Viterbi, 1 = LSE
  const int b    = blockIdx.x & 31;
  const int tid  = threadIdx.x;
  const int w    = tid >> 6;          // wave id: i-block [12w, 12w+12)
  const int j    = tid & 63;          // target label (padded to 64)
  const bool act = (j < LL);
  const int jl   = act ? j : (LL - 1);
  const int lanebase = 12*w;

  // lengths int32-or-int64 detection (values 128..256)
  int len;
  {
    bool is64 = (len_raw[1] == 0) && (len_raw[3] == 0) && (len_raw[5] == 0);
    len = is64 ? len_raw[2*b] : len_raw[b];
    if (len > TT) len = TT;
    if (len < 1) len = 1;
  }

  __shared__ float ring[8*ROWF];          // 72 KiB, 8-row ring (2 halves)
  __shared__ float partVal[2][4][NL];
  __shared__ int   partIdx[2][4][NL];
  __shared__ unsigned char bp[TT*LL];
  __shared__ unsigned char cmp_[16*LL];
  __shared__ unsigned char entry_[16];
  __shared__ unsigned char raw[TT];

  const float* em_lane = em + (size_t)b*TT*ROWF + 4*j;   // 16B/lane slice

  float trg[12];
  #pragma unroll
  for (int k = 0; k < 12; ++k) trg[k] = tr[(12*w+k)*LL + jl];

  // prologue: stage rows 0-3 (half 0) and 4-7 (half 1); G0 must land.
  ISSUE_GROUP(0, 0);
  ISSUE_GROUP(4, 4*ROWF);
  asm volatile("s_waitcnt vmcnt(9)" ::: "memory");
  __builtin_amdgcn_s_barrier();
  FENCE();

  const float init = ring[LSTART*LL + jl] + tr[LSTART*LL + jl];

  if (role == 0) {
    for (int idx = tid; idx < LL; idx += 256) bp[idx] = (unsigned char)LSTART;
    for (int idx = len*LL + tid; idx < TT*LL; idx += 256) bp[idx] = (unsigned char)LEND;

    float vbest = act ? init : -INFINITY;
    float etrA[12], etrB[12];
    { const float* lp_ = ring + ROWF + jl;   // row 1 (slot 1)
      #pragma unroll
      for (int k = 0; k < 12; ++k) etrA[k] = lp_[(12*w+k)*LL] + trg[k]; }

    #pragma unroll 1
    for (int it = 0; it < 63; ++it) {
      const int t0 = 4*it + 1;
      STEP_V(etrA, etrB, t0,     WAIT_PLAIN);
      STEP_V(etrB, etrA, t0 + 1, WAIT_VM0);
      { int gr0 = 4*it + 8; if (gr0 > 252) gr0 = 252;
        ISSUE_GROUP(gr0, (size_t)(it & 1)*4*ROWF); }
      STEP_V(etrA, etrB, t0 + 2, WAIT_PLAIN);
      STEP_V(etrB, etrA, t0 + 3, WAIT_PLAIN);
    }
    STEP_V(etrA, etrB, 253, WAIT_PLAIN);
    STEP_V(etrB, etrA, 254, WAIT_VM0);
    STEP_V(etrA, etrB, 255, WAIT_PLAIN);

    if (tid == LEND) ws[BB + b] = vbest;   // best[END]
    __syncthreads();

    // ---- traceback, chunked (16 chunks x 16 steps) ----
    for (int idx = tid; idx < 16*LL; idx += 256) {
      int c = idx / LL, l = idx - c*LL;
      int pc = l;
      #pragma unroll
      for (int k = 15; k >= 0; --k) pc = bp[(16*c + k)*LL + pc];
      cmp_[c*LL + l] = (unsigned char)pc;
    }
    __syncthreads();
    if (tid == 0) {
      int pc = LEND;
      for (int c = 15; c >= 0; --c) { entry_[c] = (unsigned char)pc; pc = cmp_[c*LL + pc]; }
    }
    __syncthreads();
    if (tid < 16) {
      int c = tid, pc = entry_[c];
      #pragma unroll
      for (int k = 15; k >= 0; --k) { int t2 = 16*c + k; pc = bp[t2*LL + pc]; raw[t2] = (unsigned char)pc; }
    }
    __syncthreads();
    out[(size_t)b*TT + tid] = (tid < TT - 1) ? (float)raw[tid + 1] : (float)LEND;
  } else {
    float vupto2 = act ? init * LOG2E : -INFINITY;
    float msh2 = RL(vupto2, 0);
    float etrA[12], etrB[12];
    { const float* lp_ = ring + ROWF + jl;
      #pragma unroll
      for (int k = 0; k < 12; ++k) etrA[k] = (lp_[(12*w+k)*LL] + trg[k]) * LOG2E; }

    #pragma unroll 1
    for (int it = 0; it < 63; ++it) {
      const int t0 = 4*it + 1;
      STEP_L(etrA, etrB, t0,     WAIT_PLAIN);
      STEP_L(etrB, etrA, t0 + 1, WAIT_VM0);
      { int gr0 = 4*it + 8; if (gr0 > 252) gr0 = 252;
        ISSUE_GROUP(gr0, (size_t)(it & 1)*4*ROWF); }
      STEP_L(etrA, etrB, t0 + 2, WAIT_PLAIN);
      STEP_L(etrB, etrA, t0 + 3, WAIT_PLAIN);
    }
    STEP_L(etrA, etrB, 253, WAIT_PLAIN);
    STEP_L(etrB, etrA, 254, WAIT_VM0);
    STEP_L(etrA, etrB, 255, WAIT_PLAIN);

    if (tid == LEND) ws[b] = vupto2 * LN2;   // upto[END] in nats
  }
}

__global__ void viterbi_score(const float* __restrict__ ws, float* __restrict__ out)
{
  int b = threadIdx.x;
  if (b < BB) out[(size_t)BB*TT + b] = ws[BB + b] - ws[b];  // best - upto
}

extern "C" void kernel_launch(void* const* d_in, const int* in_sizes, int n_in,
                              void* d_out, int out_size, void* d_ws, size_t ws_size,
                              hipStream_t stream) {
  const float* em  = (const float*)d_in[0];
  const float* tr  = (const float*)d_in[1];
  const int*   ln  = (const int*)d_in[2];
  float* out = (float*)d_out;
  float* ws  = (float*)d_ws;
  viterbi_fwd<<<dim3(64), dim3(256), 0, stream>>>(em, tr, ln, out, ws);
  viterbi_score<<<dim3(1), dim3(64), 0, stream>>>(ws, out);
}